// Round 2
// baseline (30680.789 us; speedup 1.0000x reference)
//
#include <hip/hip_runtime.h>
#include <hip/hip_fp16.h>
#include <math.h>

#define N 1024
#define W1 64
#define W2 128
#define Q 32
#define NB 32
#define NTHR 512
#define CHEB_M 16
#define ROUNDS 6
#define NITER 6
#define NEWT 20
#define JSWEEPS 6
#define CCIT 16

// ---------------- device state ----------------
__device__ unsigned g_bar;
__device__ unsigned short g_idx1[N*W1];
__device__ float g_a0[N*W1], g_u[N*W1], g_unew[N*W1], g_s[N*W1], g_snew[N*W1];
__device__ int   g_nnz1[N], g_nnz2[N];
__device__ unsigned g_rowp[N*W2];          // (idx<<16) | f16(weight)
__device__ float g_w2[N*W2], g_w2fin[N*W2];
__device__ float g_deg[N], g_sn[N];
__device__ float g_Sd[N*N];
__device__ float g_X[Q*N], g_Y[Q*N];       // column-major: col*N + row
__device__ float g_F[N*8], g_Fc[N*8];
__device__ int   g_lab[N], g_lab2[N];

__device__ __forceinline__ unsigned packrw(unsigned j, float w) {
  __half h = __float2half_rn(w);
  unsigned short bits; __builtin_memcpy(&bits, &h, 2);
  return (j << 16) | (unsigned)bits;
}
__device__ __forceinline__ float unpackw(unsigned v) {
  unsigned short bits = (unsigned short)(v & 0xFFFFu);
  __half h; __builtin_memcpy(&h, &bits, 2);
  return __half2float(h);
}

__global__ __launch_bounds__(NTHR) void mega(const float* __restrict__ A, float* __restrict__ out) {
  const int c  = blockIdx.x;
  const int t  = threadIdx.x;
  const int wv = t >> 6;
  const int ln = t & 63;

  __shared__ float sc[3][N];
  __shared__ double sM1[Q][Q];
  __shared__ double sM2[Q][Q];
  __shared__ float sStgA[32][33];
  __shared__ float sStgB[32][33];
  __shared__ double sTheta[Q];
  __shared__ int   sPerm[Q];
  __shared__ float sCoef[CHEB_M*3];
  __shared__ float sRed[8];
  __shared__ double sCs[16][2];
  __shared__ int   sPr[16], sQr[16];
  __shared__ float sB_, sA_, sLamV;
  __shared__ int   sDoneV, sF0, sF1;

  unsigned bcnt = 0;

  auto GBAR = [&]() {
    __syncthreads();
    ++bcnt;
    if (t == 0) {
      __hip_atomic_fetch_add(&g_bar, 1u, __ATOMIC_RELEASE, __HIP_MEMORY_SCOPE_AGENT);
      unsigned tgt = bcnt * (unsigned)NB;
      while (__hip_atomic_load(&g_bar, __ATOMIC_ACQUIRE, __HIP_MEMORY_SCOPE_AGENT) < tgt)
        __builtin_amdgcn_s_sleep(1);
    }
    __syncthreads();
  };

  auto DEFL = [&](float* buf) {
    __syncthreads();
    if (c == 0) {
      for (int i = t; i < N; i += NTHR) buf[i] = 0.03125f;
    } else {
      float sacc = 0.f;
      for (int i = t; i < N; i += NTHR) sacc += buf[i];
      for (int o = 32; o; o >>= 1) sacc += __shfl_xor(sacc, o);
      if (ln == 0) sRed[wv] = sacc;
      __syncthreads();
      float tot = 0.f;
      #pragma unroll
      for (int w = 0; w < 8; w++) tot += sRed[w];
      float mean = tot / (float)N;
      for (int i = t; i < N; i += NTHR) buf[i] -= mean;
    }
    __syncthreads();
  };

  auto CHSTEP = [&](float* cur, float* prv, float* nxt, float al, float be, float ga) {
    for (int i = t; i < N; i += NTHR) {
      int base = i * W2, nz = g_nnz2[i];
      float acc = 0.f;
      for (int k2 = 0; k2 < nz; k2++) {
        unsigned pv = g_rowp[base + k2];
        acc += unpackw(pv) * cur[pv >> 16];
      }
      float xc = cur[i];
      float o = al * (g_deg[i] * xc - acc) + be * xc;
      if (ga != 0.f) o += ga * prv[i];
      nxt[i] = o;
    }
    __syncthreads();
  };

  auto LMUL = [&](float* cur, float* dst) {
    for (int i = t; i < N; i += NTHR) {
      int base = i * W2, nz = g_nnz2[i];
      float acc = 0.f;
      for (int k2 = 0; k2 < nz; k2++) {
        unsigned pv = g_rowp[base + k2];
        acc += unpackw(pv) * cur[pv >> 16];
      }
      dst[i] = g_deg[i] * cur[i] - acc;
    }
    __syncthreads();
  };

  // G[a][b] = sum_i sa[:,a]*sb[:,b]  (f64 accum) -> sM1
  auto GRAM = [&](const float* sa, const float* sb) {
    __syncthreads();
    const bool same = (sa == sb);
    const int b_ = t & 31, ag = t >> 5, ra = ag * 2;
    const int col = t >> 4, rr = (t & 15) * 2;
    double a0 = 0.0, a1 = 0.0;
    for (int i0 = 0; i0 < N; i0 += 32) {
      sStgA[col][rr]     = sa[col*N + i0 + rr];
      sStgA[col][rr + 1] = sa[col*N + i0 + rr + 1];
      if (!same) {
        sStgB[col][rr]     = sb[col*N + i0 + rr];
        sStgB[col][rr + 1] = sb[col*N + i0 + rr + 1];
      }
      __syncthreads();
      const float (*BB)[33] = same ? sStgA : sStgB;
      #pragma unroll
      for (int ii = 0; ii < 32; ii++) {
        double vb = (double)BB[b_][ii];
        a0 += (double)sStgA[ra][ii] * vb;
        a1 += (double)sStgA[ra + 1][ii] * vb;
      }
      __syncthreads();
    }
    sM1[ra][b_] = a0; sM1[ra + 1][b_] = a1;
    __syncthreads();
  };

  // chol of sM1 (in place, upper) then R^-1 -> sM2
  auto CHOLINV = [&]() {
    double fl;
    { double md = 0.0; for (int i = 0; i < Q; i++) md = fmax(md, sM1[i][i]); fl = md * 1e-13 + 1e-280; }
    for (int k = 0; k < Q; k++) {
      double dkk = sM1[k][k]; if (!(dkk > fl)) dkk = fl;
      double rkk = sqrt(dkk);
      __syncthreads();
      if (t < Q && t > k) sM1[k][t] /= rkk;
      if (t == 0) sM1[k][k] = rkk;
      __syncthreads();
      if (t < Q) {
        for (int i = k + 1; i < Q; i++)
          if (t >= i) sM1[i][t] -= sM1[k][i] * sM1[k][t];
      }
      __syncthreads();
    }
    if (t < Q) {
      int j = t;
      for (int i = 0; i < Q; i++) sM2[i][j] = 0.0;
      sM2[j][j] = 1.0 / sM1[j][j];
      for (int i = j - 1; i >= 0; i--) {
        double sacc = 0.0;
        for (int k2 = i + 1; k2 <= j; k2++) sacc += sM1[i][k2] * sM2[k2][j];
        sM2[i][j] = -sacc / sM1[i][i];
      }
    }
    __syncthreads();
  };

  auto MUL = [&](const float* src, float* dst) {
    for (int i = t; i < N; i += NTHR) {
      float acc = 0.f;
      #pragma unroll
      for (int k2 = 0; k2 < Q; k2++) acc += src[k2*N + i] * (float)sM2[k2][c];
      dst[i] = acc;
    }
    __syncthreads();
  };

  auto POWA = [&]() {
    int rl = ln & 31;
    double v = 1.0, w_ = 0.0, nrm = 1.0;
    for (int it = 0; it < 20; it++) {
      w_ = 0.0;
      for (int k2 = 0; k2 < Q; k2++) w_ += sM1[rl][k2] * __shfl(v, k2);
      nrm = 0.0;
      for (int k2 = 0; k2 < Q; k2++) { double wk = __shfl(w_, k2); nrm += wk * wk; }
      nrm = sqrt(nrm) + 1e-300;
      v = w_ / nrm;
    }
    if (t == 0) {
      float b = sB_;
      float a = (float)(nrm * 1.1);
      if (a > 0.9f * b) a = 0.9f * b;
      if (a < 0.02f * b) a = 0.02f * b;
      sA_ = a;
    }
    __syncthreads();
  };

  auto JACOBI = [&]() {
    for (int id = t; id < Q*Q; id += NTHR) sM2[id >> 5][id & 31] = ((id >> 5) == (id & 31)) ? 1.0 : 0.0;
    __syncthreads();
    for (int sw = 0; sw < JSWEEPS; sw++) {
      for (int rr2 = 0; rr2 < 31; rr2++) {
        if (t < 16) {
          int p, q;
          if (t == 0) { p = 31; q = rr2 % 31; }
          else { p = (rr2 + t) % 31; q = (rr2 + 31 - t) % 31; }
          sPr[t] = p; sQr[t] = q;
          double app = sM1[p][p], aqq = sM1[q][q], apq = sM1[p][q];
          double cth, sth;
          if (fabs(apq) < 1e-280) { cth = 1.0; sth = 0.0; }
          else {
            double ta = (aqq - app) / (2.0 * apq);
            double tt = (ta >= 0.0 ? 1.0 : -1.0) / (fabs(ta) + sqrt(1.0 + ta * ta));
            cth = 1.0 / sqrt(1.0 + tt * tt); sth = tt * cth;
          }
          sCs[t][0] = cth; sCs[t][1] = sth;
        }
        __syncthreads();
        int pi = t >> 5, cj = t & 31;
        int p = sPr[pi], q = sQr[pi];
        double cth = sCs[pi][0], sth = sCs[pi][1];
        double hp = sM1[p][cj], hq = sM1[q][cj];
        sM1[p][cj] = cth * hp - sth * hq;
        sM1[q][cj] = sth * hp + cth * hq;
        __syncthreads();
        hp = sM1[cj][p]; hq = sM1[cj][q];
        sM1[cj][p] = cth * hp - sth * hq;
        sM1[cj][q] = sth * hp + cth * hq;
        double vp = sM2[cj][p], vq = sM2[cj][q];
        sM2[cj][p] = cth * vp - sth * vq;
        sM2[cj][q] = sth * vp + cth * vq;
        __syncthreads();
      }
    }
    if (t < Q) sTheta[t] = sM1[t][t];
    __syncthreads();
  };

  auto SORTP = [&]() {
    if (t == 0) {
      double th[Q]; int pm[Q];
      for (int i = 0; i < Q; i++) { th[i] = sTheta[i]; pm[i] = i; }
      for (int i = 1; i < Q; i++) {
        double x = th[i]; int px = pm[i]; int j = i - 1;
        while (j >= 0 && th[j] > x) { th[j+1] = th[j]; pm[j+1] = pm[j]; j--; }
        th[j+1] = x; pm[j+1] = px;
      }
      for (int i = 0; i < Q; i++) { sTheta[i] = th[i]; sPerm[i] = pm[i]; }
    }
    __syncthreads();
  };

  auto EIG = [&]() {
    // bound b (redundant per block)
    float mx = 0.f;
    for (int i = t; i < N; i += NTHR) mx = fmaxf(mx, g_deg[i]);
    for (int o = 32; o; o >>= 1) mx = fmaxf(mx, __shfl_xor(mx, o));
    if (ln == 0) sRed[wv] = mx;
    __syncthreads();
    if (t == 0) {
      float mm = 0.f;
      for (int w = 0; w < 8; w++) mm = fmaxf(mm, sRed[w]);
      float b = fmaxf(2.02f * mm, 1e-3f) + 1e-6f;
      sB_ = b; sA_ = 0.5f * b;
    }
    __syncthreads();
    // init own column
    float* curp = sc[0]; float* prvp = sc[1]; float* nxtp = sc[2];
    for (int i = t; i < N; i += NTHR) {
      float v;
      if (c == 0) v = 0.03125f;
      else {
        unsigned h = (unsigned)i * 1664525u + (unsigned)c * 1013904223u + 12345u;
        h ^= h >> 16; h *= 2246822519u; h ^= h >> 13; h *= 3266489917u; h ^= h >> 16;
        v = ((float)(h & 0xFFFFFFu) / 16777216.0f) - 0.5f;
      }
      curp[i] = v;
    }
    DEFL(curp);
    for (int round = 0; round < ROUNDS; round++) {
      if (t == 0) {
        double b = sB_, a = sA_;
        double e = 0.5 * (b - a), cc = 0.5 * (b + a);
        double s1 = e / (0.0 - cc);
        sCoef[0] = (float)(s1 / e); sCoef[1] = (float)(-cc * (s1 / e)); sCoef[2] = 0.f;
        double sp = s1;
        for (int k = 1; k < CHEB_M; k++) {
          double snn = 1.0 / (2.0 / s1 - sp);
          double a2 = 2.0 * snn / e;
          sCoef[k*3] = (float)a2; sCoef[k*3+1] = (float)(-cc * a2); sCoef[k*3+2] = (float)(-sp * snn);
          sp = snn;
        }
      }
      __syncthreads();
      for (int k = 0; k < CHEB_M; k++) {
        float al = sCoef[k*3], be = sCoef[k*3+1], ga = sCoef[k*3+2];
        CHSTEP(curp, prvp, nxtp, al, be, ga);
        float* tp = prvp; prvp = curp; curp = nxtp; nxtp = tp;
        if (k == 4 || k == 9 || k == CHEB_M - 1) { DEFL(curp); DEFL(prvp); }
      }
      for (int i = t; i < N; i += NTHR) g_X[c*N + i] = curp[i];
      GBAR();
      int nqr = (round == ROUNDS - 1) ? 2 : 1;
      GRAM(g_X, g_X);
      CHOLINV();
      { float* d = prvp; MUL(g_X, d); prvp = curp; curp = d; }
      for (int i = t; i < N; i += NTHR) g_Y[c*N + i] = curp[i];
      GBAR();
      if (nqr == 2) {
        GRAM(g_Y, g_Y);
        CHOLINV();
        { float* d = prvp; MUL(g_Y, d); prvp = curp; curp = d; }
        for (int i = t; i < N; i += NTHR) g_X[c*N + i] = curp[i];
        GBAR();
        LMUL(curp, nxtp);
        for (int i = t; i < N; i += NTHR) g_Y[c*N + i] = nxtp[i];
        GBAR();
        GRAM(g_X, g_Y);   // H
        JACOBI();
        SORTP();
        if (c < 8) {
          int pc = sPerm[c];
          for (int i = t; i < N; i += NTHR) {
            float acc = 0.f;
            #pragma unroll
            for (int k2 = 0; k2 < Q; k2++) acc += g_X[k2*N + i] * (float)sM2[k2][pc];
            g_Fc[i*8 + c] = acc;
          }
        }
        GBAR();
      } else {
        LMUL(curp, nxtp);
        for (int i = t; i < N; i += NTHR) g_X[c*N + i] = nxtp[i];
        GBAR();
        GRAM(g_Y, g_X);   // H (basis in g_Y, W in g_X)
        POWA();
      }
    }
  };

  // ================= BUILD =================
  for (int s2 = 0; s2 < 4; s2++) {
    int r = c*32 + wv*4 + s2;
    int cnt = 0;
    for (int c0 = 0; c0 < N; c0 += 64) {
      int j = c0 + ln;
      float v = A[r*N + j];
      bool keep = (j != r) && (v > 0.f);
      unsigned long long m = __ballot(keep);
      int pos = __popcll(m & ((1ull << ln) - 1ull));
      if (keep) {
        int w = cnt + pos;
        if (w < W1) { g_idx1[r*W1 + w] = (unsigned short)j; g_a0[r*W1 + w] = v; }
        g_Sd[j*N + r] = v;   // transpose mark
      }
      cnt += __popcll(m);
    }
    cnt = cnt < W1 ? cnt : W1;
    if (ln == 0) g_nnz1[r] = cnt;
    g_u[r*W1 + ln] = 1.f;
    g_s[r*W1 + ln] = 0.f;
  }
  GBAR();
  for (int s2 = 0; s2 < 4; s2++) {
    int r = c*32 + wv*4 + s2;
    int cnt = 0; float dacc = 0.f;
    for (int c0 = 0; c0 < N; c0 += 64) {
      int j = c0 + ln;
      float vr = A[r*N + j];
      float vc = g_Sd[r*N + j];
      bool keep = (j != r) && (vr > 0.f || vc > 0.f);
      unsigned long long m = __ballot(keep);
      int pos = __popcll(m & ((1ull << ln) - 1ull));
      if (keep) {
        int w = cnt + pos;
        if (w < W2) {
          float val = 0.5f * (vr + vc);
          g_w2[r*W2 + w] = val; g_w2fin[r*W2 + w] = val;
          g_rowp[r*W2 + w] = packrw((unsigned)j, val);
          dacc += val;
        }
      }
      cnt += __popcll(m);
    }
    for (int o = 32; o; o >>= 1) dacc += __shfl_xor(dacc, o);
    cnt = cnt < W2 ? cnt : W2;
    if (ln == 0) { g_nnz2[r] = cnt; g_deg[r] = dacc; }
    for (int j = ln; j < N; j += 64) g_Sd[r*N + j] = 0.f;  // clear marks row
  }
  GBAR();

  if (t == 0) { sLamV = 0.01f; sDoneV = 0; }
  __syncthreads();

  // ================= initial eigensolve -> F =================
  EIG();
  for (int k2 = t; k2 < 256; k2 += NTHR) g_F[c*256 + k2] = g_Fc[c*256 + k2];
  GBAR();

  // ================= CLR iterations =================
  for (int iter = 0; iter < NITER; iter++) {
    // sn
    if (t < 32) {
      int r = c*32 + t; float ss = 0.f;
      #pragma unroll
      for (int d = 0; d < 8; d++) { float v = g_F[r*8 + d]; ss += v * v; }
      g_sn[r] = ss;
    }
    GBAR();
    // newton + scatter
    {
      float lamreg = sLamV;
      for (int s2 = 0; s2 < 4; s2++) {
        int r = c*32 + wv*4 + s2;
        int nnz = g_nnz1[r];
        bool valid = ln < nnz;
        int e = r*W1 + ln;
        int cidx = valid ? (int)g_idx1[e] : 0;
        float a0v = valid ? g_a0[e] : 0.f;
        float uu  = valid ? g_u[e]  : 1.f;
        float fr[8];
        #pragma unroll
        for (int d = 0; d < 8; d++) fr[d] = g_F[r*8 + d];
        float dot = 0.f;
        #pragma unroll
        for (int d = 0; d < 8; d++) dot += fr[d] * g_F[cidx*8 + d];
        float dist = fmaxf(g_sn[r] + g_sn[cidx] - 2.f * dot, 0.f);
        float dd = uu * a0v - 0.5f * lamreg * dist;
        float tmin = valid ? (uu - dd) : 3.0e38f;
        for (int o = 32; o; o >>= 1) tmin = fminf(tmin, __shfl_xor(tmin, o));
        float lam = (tmin < 3.0e38f) ? tmin : 0.f;
        for (int it = 0; it < NEWT; it++) {
          float v1 = (lam + dd) / uu;
          bool pos = valid && (v1 > 0.f);
          float gg = pos ? (1.f / uu) : 0.f;
          float ff = pos ? v1 : 0.f;
          for (int o = 32; o; o >>= 1) { gg += __shfl_xor(gg, o); ff += __shfl_xor(ff, o); }
          float f = ff - 1.f;
          float step = f / (gg > 0.f ? gg : 1.f);
          lam = (fabsf(f) > 1e-8f) ? (lam - step) : lam;
        }
        float v1 = (lam + dd) / uu;
        float sv = fmaxf(v1, 0.f);
        if (valid) {
          g_snew[e] = sv;
          float df = sv - a0v;
          g_unew[e] = 1.f / (2.f * sqrtf(df * df + 2.2204e-16f));
          g_Sd[r*N + cidx] = sv;
        }
      }
    }
    GBAR();
    // gather + deg
    for (int s2 = 0; s2 < 4; s2++) {
      int r = c*32 + wv*4 + s2;
      int nnz = g_nnz2[r];
      float dacc = 0.f;
      for (int k2 = ln; k2 < nnz; k2 += 64) {
        unsigned pv = g_rowp[r*W2 + k2];
        int j = pv >> 16;
        float v = 0.5f * (g_Sd[r*N + j] + g_Sd[j*N + r]);
        g_w2[r*W2 + k2] = v;
        g_rowp[r*W2 + k2] = packrw((unsigned)j, v);
        dacc += v;
      }
      for (int o = 32; o; o >>= 1) dacc += __shfl_xor(dacc, o);
      if (ln == 0) g_deg[r] = dacc;
    }
    GBAR();
    // eigensolve on fresh A_new
    EIG();
    // state (redundant per block, deterministic)
    if (t == 0) {
      double fn1 = 0.0;
      for (int i = 0; i < 8; i++) fn1 += sTheta[i];
      double fn2 = fn1 + sTheta[8];
      int done = sDoneV; float lam = sLamV;
      int c1 = (fn1 > 1e-10) ? 1 : 0;
      int c2 = ((!c1) && (fn2 < 1e-10)) ? 1 : 0;
      sF0 = !done;
      sF1 = (!done) && (!c2);
      if (!done) { if (c1) lam *= 2.f; else if (c2) lam *= 0.5f; sLamV = lam; }
      sDoneV = done || ((!c1) && (!c2));
    }
    __syncthreads();
    if (sF0) {
      for (int k2 = t; k2 < 32*W1; k2 += NTHR) { int id = c*32*W1 + k2; g_s[id] = g_snew[id]; g_u[id] = g_unew[id]; }
      for (int k2 = t; k2 < 32*W2; k2 += NTHR) { int id = c*32*W2 + k2; g_w2fin[id] = g_w2[id]; }
    }
    if (sF1) {
      for (int k2 = t; k2 < 256; k2 += NTHR) g_F[c*256 + k2] = g_Fc[c*256 + k2];
    }
    GBAR();
  }

  // ================= connected components =================
  if (t < 32) { int i2 = c*32 + t; g_lab[i2] = i2; }
  GBAR();
  for (int it2 = 0; it2 < CCIT; it2++) {
    for (int s2 = 0; s2 < 4; s2++) {
      int r = c*32 + wv*4 + s2;
      int nnz = g_nnz2[r];
      int mlab = g_lab[r];
      for (int k2 = ln; k2 < nnz; k2 += 64) {
        if (g_w2fin[r*W2 + k2] > 0.f) {
          int l2 = g_lab[(int)(g_rowp[r*W2 + k2] >> 16)];
          mlab = mlab < l2 ? mlab : l2;
        }
      }
      for (int o = 32; o; o >>= 1) { int l2 = __shfl_xor(mlab, o); mlab = mlab < l2 ? mlab : l2; }
      if (ln == 0) g_lab2[r] = mlab;
    }
    GBAR();
    if (t < 32) { int i2 = c*32 + t; g_lab[i2] = g_lab2[g_lab2[i2]]; }
    GBAR();
  }

  // ================= outputs =================
  if (t < 32) { int i2 = c*32 + t; out[i2] = (float)g_lab[i2]; }
  for (int s2 = 0; s2 < 4; s2++) {
    int r = c*32 + wv*4 + s2;
    if (ln < g_nnz1[r]) out[N + r*N + (int)g_idx1[r*W1 + ln]] = g_s[r*W1 + ln];
  }
}

extern "C" void kernel_launch(void* const* d_in, const int* in_sizes, int n_in,
                              void* d_out, int out_size, void* d_ws, size_t ws_size,
                              hipStream_t stream) {
  const float* A = (const float*)d_in[0];
  float* out = (float*)d_out;

  void *pSd, *pBar;
  hipGetSymbolAddress(&pSd,  HIP_SYMBOL(g_Sd));
  hipGetSymbolAddress(&pBar, HIP_SYMBOL(g_bar));

  hipMemsetAsync(pSd, 0, sizeof(float) * (size_t)N * N, stream);
  hipMemsetAsync(pBar, 0, sizeof(unsigned), stream);
  hipMemsetAsync(d_out, 0, sizeof(float) * (size_t)out_size, stream);

  mega<<<NB, NTHR, 0, stream>>>(A, out);
}

// Round 3
// 11253.626 us; speedup vs baseline: 2.7263x; 2.7263x over previous
//
#include <hip/hip_runtime.h>
#include <hip/hip_fp16.h>
#include <math.h>

#define N 1024
#define W1 64
#define W2S 96
#define Q 32
#define NB 32
#define NTHR 512
#define CHEB_M 16
#define ROUNDS 4
#define NITER 6
#define NEWT 20
#define JSWEEPS 6
#define CCIT 12

// ---------------- device state ----------------
__device__ unsigned g_cnt, g_gen;
__device__ unsigned short g_idx1[N*W1];
__device__ float g_a0[N*W1], g_u[N*W1], g_unew[N*W1], g_s[N*W1], g_snew[N*W1];
__device__ int g_nnz1[N], g_nnz2[N], g_nz8[N];
__device__ __align__(16) unsigned g_rowp[N*W2S];   // (idx<<16) | f16(w)
__device__ float g_w2[N*W2S], g_w2fin[N*W2S];
__device__ float g_deg[N], g_sn[N];
__device__ float g_Sd[N*N];
__device__ float g_X[Q*N], g_Y[Q*N];               // col-major
__device__ double g_G[Q*Q], g_H[Q*Q];
__device__ float g_F[N*8], g_Fc[N*8];
__device__ int g_lab[N], g_lab2[N];

__device__ __forceinline__ unsigned packrw(unsigned j, float w) {
  __half h = __float2half_rn(w);
  unsigned short bits; __builtin_memcpy(&bits, &h, 2);
  return (j << 16) | (unsigned)bits;
}
__device__ __forceinline__ float unpackw(unsigned v) {
  unsigned short bits = (unsigned short)(v & 0xFFFFu);
  __half h; __builtin_memcpy(&h, &bits, 2);
  return __half2float(h);
}

#define P1(pv) { unsigned _p = (pv); acc += __half2float(__ushort_as_half((unsigned short)(_p & 0xFFFFu))) * xc[_p >> 16]; }

__global__ __launch_bounds__(NTHR) void mega(const float* __restrict__ A, float* __restrict__ out) {
  const int c = blockIdx.x;
  const int t = threadIdx.x;
  const int wv = t >> 6, ln = t & 63;

  __shared__ float xv[3][N];
  __shared__ float wl[N];
  __shared__ float degl[N];
  __shared__ double sM1[Q][Q+1];
  __shared__ double sM2[Q][Q+1];
  __shared__ double sTheta[Q];
  __shared__ int   sPerm[Q];
  __shared__ float sCoef[CHEB_M*3];
  __shared__ float sRed[8];
  __shared__ double sCs[16][2];
  __shared__ int   sPr[16], sQr[16];
  __shared__ float sB_, sA_, sLamV;
  __shared__ int   sDoneV, sF0, sF1;

  float* xb = &xv[0][0];
  unsigned bcnt = 0;

  auto GBAR = [&]() {
    __syncthreads();
    ++bcnt;
    if (t == 0) {
      unsigned old = __hip_atomic_fetch_add(&g_cnt, 1u, __ATOMIC_ACQ_REL, __HIP_MEMORY_SCOPE_AGENT);
      if (old == (unsigned)NB - 1u) {
        __hip_atomic_store(&g_cnt, 0u, __ATOMIC_RELAXED, __HIP_MEMORY_SCOPE_AGENT);
        __hip_atomic_store(&g_gen, bcnt, __ATOMIC_RELEASE, __HIP_MEMORY_SCOPE_AGENT);
      } else {
        while (__hip_atomic_load(&g_gen, __ATOMIC_ACQUIRE, __HIP_MEMORY_SCOPE_AGENT) < bcnt)
          __builtin_amdgcn_s_sleep(2);
      }
    }
    __syncthreads();
  };

  // pipelined sparse row dot: sum_k w_k * xc[j_k]
  auto SPROW = [&](const float* __restrict__ xc, int r) -> float {
    int nz8 = g_nz8[r];
    const uint4* __restrict__ rp4 = (const uint4*)&g_rowp[r*W2S];
    float acc = 0.f;
    uint4 pA = rp4[0], pB = rp4[1];
    for (int kb = 8; kb < nz8; kb += 8) {
      uint4 nA = rp4[kb >> 2], nB = rp4[(kb >> 2) + 1];
      P1(pA.x) P1(pA.y) P1(pA.z) P1(pA.w)
      P1(pB.x) P1(pB.y) P1(pB.z) P1(pB.w)
      pA = nA; pB = nB;
    }
    P1(pA.x) P1(pA.y) P1(pA.z) P1(pA.w)
    P1(pB.x) P1(pB.y) P1(pB.z) P1(pB.w)
    return acc;
  };

  auto CHSTEP = [&](int cu, int pv_, int nx, float al, float be, float ga) {
    const float* xc = xb + cu*N;
    #pragma unroll
    for (int rr = 0; rr < 2; rr++) {
      int r = t + rr*512;
      float acc = SPROW(xc, r);
      float xr = xc[r];
      float o = al*(degl[r]*xr - acc) + be*xr;
      if (ga != 0.f) o += ga * xb[pv_*N + r];
      xb[nx*N + r] = o;
    }
    __syncthreads();
  };

  auto LMUL = [&](int cu) {
    const float* xc = xb + cu*N;
    #pragma unroll
    for (int rr = 0; rr < 2; rr++) {
      int r = t + rr*512;
      float acc = SPROW(xc, r);
      wl[r] = degl[r]*xc[r] - acc;
    }
    __syncthreads();
  };

  auto DEFL = [&](int bu) {
    __syncthreads();
    if (c == 0) {
      xb[bu*N + t] = 0.03125f;
      xb[bu*N + 512 + t] = 0.03125f;
    } else {
      float s = xb[bu*N + t] + xb[bu*N + 512 + t];
      for (int o = 32; o; o >>= 1) s += __shfl_xor(s, o);
      if (ln == 0) sRed[wv] = s;
      __syncthreads();
      float tot = 0.f;
      #pragma unroll
      for (int w = 0; w < 8; w++) tot += sRed[w];
      float mean = tot / (float)N;
      xb[bu*N + t] -= mean;
      xb[bu*N + 512 + t] -= mean;
    }
    __syncthreads();
  };

  auto WRITECOL = [&](float* M, int cu) {
    M[c*N + t] = xb[cu*N + t];
    M[c*N + 512 + t] = xb[cu*N + 512 + t];
  };

  auto GROW = [&](const float* M, int cu) {   // g_G row c = x_c . cols(M)
    const float* xc = xb + cu*N;
    for (int bb = wv; bb < Q; bb += 8) {
      const float* mc = M + bb*N;
      double p = 0.0;
      for (int k = 0; k < 16; k++) {
        int i = ln + k*64;
        p += (double)xc[i] * (double)mc[i];
      }
      for (int o = 32; o; o >>= 1) p += __shfl_xor(p, o);
      if (ln == 0) g_G[c*Q + bb] = p;
    }
  };

  auto HCOL = [&](const float* M) {           // g_H[:,c] = cols(M) . wl
    for (int bb = wv; bb < Q; bb += 8) {
      const float* mc = M + bb*N;
      double p = 0.0;
      for (int k = 0; k < 16; k++) {
        int i = ln + k*64;
        p += (double)wl[i] * (double)mc[i];
      }
      for (int o = 32; o; o >>= 1) p += __shfl_xor(p, o);
      if (ln == 0) g_H[bb*Q + c] = p;
    }
  };

  auto CHOLINV = [&]() {                      // g_G -> chol -> sM2 = R^-1
    for (int id = t; id < Q*Q; id += NTHR) sM1[id>>5][id&31] = g_G[id];
    __syncthreads();
    double fl;
    { double md = 0.0; for (int i = 0; i < Q; i++) md = fmax(md, sM1[i][i]); fl = md*1e-13 + 1e-280; }
    for (int k = 0; k < Q; k++) {
      double dkk = sM1[k][k]; if (!(dkk > fl)) dkk = fl;
      double rkk = sqrt(dkk);
      __syncthreads();
      if (t < Q && t > k) sM1[k][t] /= rkk;
      if (t == 0) sM1[k][k] = rkk;
      __syncthreads();
      if (t < Q) for (int i = k+1; i < Q; i++) if (t >= i) sM1[i][t] -= sM1[k][i]*sM1[k][t];
      __syncthreads();
    }
    if (t < Q) {
      int j = t;
      for (int i = 0; i < Q; i++) sM2[i][j] = 0.0;
      sM2[j][j] = 1.0/sM1[j][j];
      for (int i = j-1; i >= 0; i--) {
        double sa = 0.0;
        for (int k2 = i+1; k2 <= j; k2++) sa += sM1[i][k2]*sM2[k2][j];
        sM2[i][j] = -sa/sM1[i][i];
      }
    }
    __syncthreads();
  };

  auto MULR = [&](const float* M, int tb) {   // x_c(new) = M * R^-1[:,c]
    float ric[Q];
    #pragma unroll
    for (int k = 0; k < Q; k++) ric[k] = (float)sM2[k][c];
    #pragma unroll
    for (int rr = 0; rr < 2; rr++) {
      int i = t + rr*512;
      float acc = 0.f;
      #pragma unroll
      for (int k = 0; k < Q; k++) acc += M[k*N + i]*ric[k];
      xb[tb*N + i] = acc;
    }
    __syncthreads();
  };

  auto POWA = [&]() {
    for (int id = t; id < Q*Q; id += NTHR) sM1[id>>5][id&31] = g_H[id];
    __syncthreads();
    int rl = ln & 31;
    double v = 1.0, w_ = 0.0, nrm = 1.0;
    for (int it = 0; it < 20; it++) {
      w_ = 0.0;
      for (int k2 = 0; k2 < Q; k2++) w_ += sM1[rl][k2]*__shfl(v, k2);
      nrm = 0.0;
      for (int k2 = 0; k2 < Q; k2++) { double wk = __shfl(w_, k2); nrm += wk*wk; }
      nrm = sqrt(nrm) + 1e-300;
      v = w_/nrm;
    }
    if (t == 0) {
      float b = sB_;
      float a = (float)(nrm*1.1);
      if (a > 0.9f*b) a = 0.9f*b;
      if (a < 0.02f*b) a = 0.02f*b;
      sA_ = a;
    }
    __syncthreads();
  };

  auto JACOBI = [&]() {
    for (int id = t; id < Q*Q; id += NTHR) {
      sM1[id>>5][id&31] = g_H[id];
      sM2[id>>5][id&31] = ((id>>5) == (id&31)) ? 1.0 : 0.0;
    }
    __syncthreads();
    for (int sw = 0; sw < JSWEEPS; sw++) {
      for (int rr2 = 0; rr2 < 31; rr2++) {
        if (t < 16) {
          int p, q;
          if (t == 0) { p = 31; q = rr2 % 31; }
          else { p = (rr2 + t) % 31; q = (rr2 + 31 - t) % 31; }
          sPr[t] = p; sQr[t] = q;
          double app = sM1[p][p], aqq = sM1[q][q], apq = sM1[p][q];
          double cth, sth;
          if (fabs(apq) < 1e-280) { cth = 1.0; sth = 0.0; }
          else {
            double ta = (aqq - app)/(2.0*apq);
            double tt = (ta >= 0.0 ? 1.0 : -1.0)/(fabs(ta) + sqrt(1.0 + ta*ta));
            cth = 1.0/sqrt(1.0 + tt*tt); sth = tt*cth;
          }
          sCs[t][0] = cth; sCs[t][1] = sth;
        }
        __syncthreads();
        int pi = t >> 5, cj = t & 31;
        int p = sPr[pi], q = sQr[pi];
        double cth = sCs[pi][0], sth = sCs[pi][1];
        double hp = sM1[p][cj], hq = sM1[q][cj];
        sM1[p][cj] = cth*hp - sth*hq;
        sM1[q][cj] = sth*hp + cth*hq;
        __syncthreads();
        hp = sM1[cj][p]; hq = sM1[cj][q];
        sM1[cj][p] = cth*hp - sth*hq;
        sM1[cj][q] = sth*hp + cth*hq;
        double vp = sM2[cj][p], vq = sM2[cj][q];
        sM2[cj][p] = cth*vp - sth*vq;
        sM2[cj][q] = sth*vp + cth*vq;
        __syncthreads();
      }
    }
    if (t < Q) sTheta[t] = sM1[t][t];
    __syncthreads();
  };

  auto SORTP = [&]() {
    if (t == 0) {
      double th[Q]; int pm[Q];
      for (int i = 0; i < Q; i++) { th[i] = sTheta[i]; pm[i] = i; }
      for (int i = 1; i < Q; i++) {
        double x = th[i]; int px = pm[i]; int j = i - 1;
        while (j >= 0 && th[j] > x) { th[j+1] = th[j]; pm[j+1] = pm[j]; j--; }
        th[j+1] = x; pm[j+1] = px;
      }
      for (int i = 0; i < Q; i++) { sTheta[i] = th[i]; sPerm[i] = pm[i]; }
    }
    __syncthreads();
  };

  auto EIG = [&]() {
    degl[t] = g_deg[t]; degl[t+512] = g_deg[t+512];
    __syncthreads();
    float mx = fmaxf(degl[t], degl[t+512]);
    for (int o = 32; o; o >>= 1) mx = fmaxf(mx, __shfl_xor(mx, o));
    if (ln == 0) sRed[wv] = mx;
    __syncthreads();
    if (t == 0) {
      float mm = 0.f;
      for (int w = 0; w < 8; w++) mm = fmaxf(mm, sRed[w]);
      float b = fmaxf(2.02f*mm, 1e-3f) + 1e-6f;
      sB_ = b; sA_ = 0.5f*b;
    }
    __syncthreads();
    // init buf0
    #pragma unroll
    for (int rr = 0; rr < 2; rr++) {
      int i = t + rr*512;
      float v;
      if (c == 0) v = 0.03125f;
      else {
        unsigned h = (unsigned)i*1664525u + (unsigned)c*1013904223u + 12345u;
        h ^= h >> 16; h *= 2246822519u; h ^= h >> 13; h *= 3266489917u; h ^= h >> 16;
        v = ((float)(h & 0xFFFFFFu)/16777216.f) - 0.5f;
      }
      xb[i] = v;
    }
    DEFL(0);
    int cu = 0;
    for (int round = 0; round < ROUNDS; round++) {
      if (t == 0) {
        double b = sB_, a = sA_;
        double e = 0.5*(b - a), cc = 0.5*(b + a);
        double s1 = e/(0.0 - cc);
        sCoef[0] = (float)(s1/e); sCoef[1] = (float)(-cc*(s1/e)); sCoef[2] = 0.f;
        double sp = s1;
        for (int k = 1; k < CHEB_M; k++) {
          double snn = 1.0/(2.0/s1 - sp);
          double a2 = 2.0*snn/e;
          sCoef[k*3] = (float)a2; sCoef[k*3+1] = (float)(-cc*a2); sCoef[k*3+2] = (float)(-sp*snn);
          sp = snn;
        }
      }
      __syncthreads();
      int pv_ = (cu+1)%3, nx = (cu+2)%3;
      for (int k = 0; k < CHEB_M; k++) {
        CHSTEP(cu, pv_, nx, sCoef[k*3], sCoef[k*3+1], sCoef[k*3+2]);
        int op = pv_; pv_ = cu; cu = nx; nx = op;
        if (k == 4 || k == 9 || k == CHEB_M-1) { DEFL(cu); DEFL(pv_); }
      }
      WRITECOL(g_X, cu);
      GBAR();
      GROW(g_X, cu);
      GBAR();
      CHOLINV();
      { int tb = (cu+1)%3; MULR(g_X, tb); cu = tb; }
      WRITECOL(g_Y, cu);
      GBAR();
      if (round < ROUNDS-1) {
        LMUL(cu);
        HCOL(g_Y);
        GBAR();
        POWA();
      } else {
        GROW(g_Y, cu);
        GBAR();
        CHOLINV();
        { int tb = (cu+1)%3; MULR(g_Y, tb); cu = tb; }
        WRITECOL(g_X, cu);
        GBAR();
        LMUL(cu);
        HCOL(g_X);
        GBAR();
        JACOBI();
        SORTP();
        if (c < 8) {
          int pc = sPerm[c];
          float vc_[Q];
          #pragma unroll
          for (int k = 0; k < Q; k++) vc_[k] = (float)sM2[k][pc];
          #pragma unroll
          for (int rr = 0; rr < 2; rr++) {
            int i = t + rr*512;
            float acc = 0.f;
            #pragma unroll
            for (int k = 0; k < Q; k++) acc += g_X[k*N + i]*vc_[k];
            g_Fc[i*8 + c] = acc;
          }
        }
        GBAR();
      }
    }
  };

  // ================= BUILD =================
  for (int s2 = 0; s2 < 4; s2++) {
    int r = c*32 + wv*4 + s2;
    int cnt = 0;
    for (int c0 = 0; c0 < N; c0 += 64) {
      int j = c0 + ln;
      float v = A[r*N + j];
      bool keep = (j != r) && (v > 0.f);
      unsigned long long m = __ballot(keep);
      int pos = __popcll(m & ((1ull << ln) - 1ull));
      if (keep) {
        int w = cnt + pos;
        if (w < W1) { g_idx1[r*W1 + w] = (unsigned short)j; g_a0[r*W1 + w] = v; }
        g_Sd[j*N + r] = v;   // transpose mark
      }
      cnt += __popcll(m);
    }
    cnt = cnt < W1 ? cnt : W1;
    if (ln == 0) g_nnz1[r] = cnt;
    g_u[r*W1 + ln] = 1.f;
    g_s[r*W1 + ln] = 0.f;
  }
  GBAR();
  for (int s2 = 0; s2 < 4; s2++) {
    int r = c*32 + wv*4 + s2;
    int cnt = 0; float dacc = 0.f;
    for (int c0 = 0; c0 < N; c0 += 64) {
      int j = c0 + ln;
      float vr = A[r*N + j];
      float vc = g_Sd[r*N + j];
      bool keep = (j != r) && (vr > 0.f || vc > 0.f);
      unsigned long long m = __ballot(keep);
      int pos = __popcll(m & ((1ull << ln) - 1ull));
      if (keep) {
        int w = cnt + pos;
        if (w < W2S) {
          float val = 0.5f*(vr + vc);
          unsigned pv = packrw((unsigned)j, val);
          g_rowp[r*W2S + w] = pv;
          g_w2[r*W2S + w] = val;
          g_w2fin[r*W2S + w] = val;
          dacc += unpackw(pv);
        }
      }
      cnt += __popcll(m);
    }
    for (int o = 32; o; o >>= 1) dacc += __shfl_xor(dacc, o);
    cnt = cnt < W2S ? cnt : W2S;
    int nz8 = (cnt + 7) & ~7; if (nz8 < 8) nz8 = 8;
    if (ln == 0) { g_nnz2[r] = cnt; g_nz8[r] = nz8; g_deg[r] = dacc; }
    for (int w = cnt + ln; w < W2S; w += 64) {
      g_rowp[r*W2S + w] = ((unsigned)r) << 16;
      g_w2[r*W2S + w] = 0.f;
      g_w2fin[r*W2S + w] = 0.f;
    }
    for (int j = ln; j < N; j += 64) g_Sd[r*N + j] = 0.f;
  }
  GBAR();

  if (t == 0) { sLamV = 0.01f; sDoneV = 0; }
  __syncthreads();

  // ================= initial eigensolve -> F =================
  EIG();
  for (int k2 = t; k2 < 256; k2 += NTHR) g_F[c*256 + k2] = g_Fc[c*256 + k2];
  GBAR();

  // ================= CLR iterations =================
  for (int iter = 0; iter < NITER; iter++) {
    if (t < 32) {
      int r = c*32 + t; float ss = 0.f;
      #pragma unroll
      for (int d = 0; d < 8; d++) { float v = g_F[r*8 + d]; ss += v*v; }
      g_sn[r] = ss;
    }
    GBAR();
    {
      float lamreg = sLamV;
      for (int s2 = 0; s2 < 4; s2++) {
        int r = c*32 + wv*4 + s2;
        int nnz = g_nnz1[r];
        bool valid = ln < nnz;
        int e = r*W1 + ln;
        int cidx = valid ? (int)g_idx1[e] : 0;
        float a0v = valid ? g_a0[e] : 0.f;
        float uu = valid ? g_u[e] : 1.f;
        float fr[8];
        #pragma unroll
        for (int d = 0; d < 8; d++) fr[d] = g_F[r*8 + d];
        float dot = 0.f;
        #pragma unroll
        for (int d = 0; d < 8; d++) dot += fr[d]*g_F[cidx*8 + d];
        float dist = fmaxf(g_sn[r] + g_sn[cidx] - 2.f*dot, 0.f);
        float dd = uu*a0v - 0.5f*lamreg*dist;
        float tmin = valid ? (uu - dd) : 3.0e38f;
        for (int o = 32; o; o >>= 1) tmin = fminf(tmin, __shfl_xor(tmin, o));
        float lam = (tmin < 3.0e38f) ? tmin : 0.f;
        for (int it = 0; it < NEWT; it++) {
          float v1 = (lam + dd)/uu;
          bool pos = valid && (v1 > 0.f);
          float gg = pos ? (1.f/uu) : 0.f;
          float ff = pos ? v1 : 0.f;
          for (int o = 32; o; o >>= 1) { gg += __shfl_xor(gg, o); ff += __shfl_xor(ff, o); }
          float f = ff - 1.f;
          float step = f/(gg > 0.f ? gg : 1.f);
          lam = (fabsf(f) > 1e-8f) ? (lam - step) : lam;
        }
        float v1 = (lam + dd)/uu;
        float sv = fmaxf(v1, 0.f);
        if (valid) {
          g_snew[e] = sv;
          float df = sv - a0v;
          g_unew[e] = 1.f/(2.f*sqrtf(df*df + 2.2204e-16f));
          g_Sd[r*N + cidx] = sv;
        }
      }
    }
    GBAR();
    for (int s2 = 0; s2 < 4; s2++) {
      int r = c*32 + wv*4 + s2;
      int nnz = g_nnz2[r];
      float dacc = 0.f;
      for (int k2 = ln; k2 < nnz; k2 += 64) {
        unsigned pv = g_rowp[r*W2S + k2];
        int j = pv >> 16;
        float v = 0.5f*(g_Sd[r*N + j] + g_Sd[j*N + r]);
        unsigned np = packrw((unsigned)j, v);
        g_w2[r*W2S + k2] = v;
        g_rowp[r*W2S + k2] = np;
        dacc += unpackw(np);
      }
      for (int o = 32; o; o >>= 1) dacc += __shfl_xor(dacc, o);
      if (ln == 0) g_deg[r] = dacc;
    }
    GBAR();
    EIG();
    if (t == 0) {
      double fn1 = 0.0;
      for (int i = 0; i < 8; i++) fn1 += sTheta[i];
      double fn2 = fn1 + sTheta[8];
      int done = sDoneV; float lam = sLamV;
      int c1 = (fn1 > 1e-10) ? 1 : 0;
      int c2 = ((!c1) && (fn2 < 1e-10)) ? 1 : 0;
      sF0 = !done;
      sF1 = (!done) && (!c2);
      if (!done) { if (c1) lam *= 2.f; else if (c2) lam *= 0.5f; sLamV = lam; }
      sDoneV = done || ((!c1) && (!c2));
    }
    __syncthreads();
    if (sF0) {
      for (int k2 = t; k2 < 32*W1; k2 += NTHR) { int id = c*32*W1 + k2; g_s[id] = g_snew[id]; g_u[id] = g_unew[id]; }
      for (int k2 = t; k2 < 32*W2S; k2 += NTHR) { int id = c*32*W2S + k2; g_w2fin[id] = g_w2[id]; }
    }
    if (sF1) {
      for (int k2 = t; k2 < 256; k2 += NTHR) g_F[c*256 + k2] = g_Fc[c*256 + k2];
    }
    GBAR();
  }

  // ================= connected components =================
  if (t < 32) { int i2 = c*32 + t; g_lab[i2] = i2; }
  GBAR();
  for (int it2 = 0; it2 < CCIT; it2++) {
    for (int s2 = 0; s2 < 4; s2++) {
      int r = c*32 + wv*4 + s2;
      int nnz = g_nnz2[r];
      int mlab = g_lab[r];
      for (int k2 = ln; k2 < nnz; k2 += 64) {
        if (g_w2fin[r*W2S + k2] > 0.f) {
          int l2 = g_lab[(int)(g_rowp[r*W2S + k2] >> 16)];
          mlab = mlab < l2 ? mlab : l2;
        }
      }
      for (int o = 32; o; o >>= 1) { int l2 = __shfl_xor(mlab, o); mlab = mlab < l2 ? mlab : l2; }
      if (ln == 0) g_lab2[r] = mlab;
    }
    GBAR();
    if (t < 32) { int i2 = c*32 + t; g_lab[i2] = g_lab2[g_lab2[i2]]; }
    GBAR();
  }

  // ================= outputs =================
  if (t < 32) { int i2 = c*32 + t; out[i2] = (float)g_lab[i2]; }
  for (int s2 = 0; s2 < 4; s2++) {
    int r = c*32 + wv*4 + s2;
    if (ln < g_nnz1[r]) out[N + r*N + (int)g_idx1[r*W1 + ln]] = g_s[r*W1 + ln];
  }
}

extern "C" void kernel_launch(void* const* d_in, const int* in_sizes, int n_in,
                              void* d_out, int out_size, void* d_ws, size_t ws_size,
                              hipStream_t stream) {
  const float* A = (const float*)d_in[0];
  float* out = (float*)d_out;

  void *pSd, *pCnt, *pGen;
  hipGetSymbolAddress(&pSd,  HIP_SYMBOL(g_Sd));
  hipGetSymbolAddress(&pCnt, HIP_SYMBOL(g_cnt));
  hipGetSymbolAddress(&pGen, HIP_SYMBOL(g_gen));

  hipMemsetAsync(pSd, 0, sizeof(float)*(size_t)N*N, stream);
  hipMemsetAsync(pCnt, 0, sizeof(unsigned), stream);
  hipMemsetAsync(pGen, 0, sizeof(unsigned), stream);
  hipMemsetAsync(d_out, 0, sizeof(float)*(size_t)out_size, stream);

  mega<<<NB, NTHR, 0, stream>>>(A, out);
}